// Round 4
// baseline (370.440 us; speedup 1.0000x reference)
//
#include <hip/hip_runtime.h>

#define NU 100000
#define NI 50000
#define NE 1000000
#define D  64
#define NBI 196            // item buckets, 256 items each
#define NBU 391            // user buckets, 256 users each
#define NB_TOT (NBI + NBU)
#define CHUNK 4096         // edges per k_part block (16 per thread)

__device__ __forceinline__ unsigned short f2bf(float f) {
    unsigned int u = __float_as_uint(f);
    u += 0x7FFFu + ((u >> 16) & 1u);   // round-to-nearest-even
    return (unsigned short)(u >> 16);
}
__device__ __forceinline__ float bf2f(unsigned short h) {
    return __uint_as_float(((unsigned int)h) << 16);
}

// ---- f32 table -> bf16 shadow table (vectorized 4-wide) ----
__global__ void k_tobf16(const float* __restrict__ in, unsigned short* __restrict__ out, int n4) {
    int i = blockIdx.x * blockDim.x + threadIdx.x;
    if (i < n4) {
        float4 f = ((const float4*)in)[i];
        ushort4 h;
        h.x = f2bf(f.x); h.y = f2bf(f.y); h.z = f2bf(f.z); h.w = f2bf(f.w);
        ((ushort4*)out)[i] = h;
    }
}

// ---- bucket histograms for both partitions in one pass ----
__global__ void k_bhist(const int* __restrict__ esrc, const int* __restrict__ edst,
                        int* __restrict__ bcnt, int ne) {
    __shared__ int h[NB_TOT];
    for (int b = threadIdx.x; b < NB_TOT; b += blockDim.x) h[b] = 0;
    __syncthreads();
    int stride = gridDim.x * blockDim.x;
    for (int e = blockIdx.x * blockDim.x + threadIdx.x; e < ne; e += stride) {
        atomicAdd(&h[edst[e] >> 8], 1);
        atomicAdd(&h[NBI + (esrc[e] >> 8)], 1);
    }
    __syncthreads();
    for (int b = threadIdx.x; b < NB_TOT; b += blockDim.x) {
        int v = h[b];
        if (v) atomicAdd(&bcnt[b], v);
    }
}

// ---- tiny exclusive scan of bucket counts -> bucket bases + partition cursors ----
__global__ void k_bscan(const int* __restrict__ bcnt, int* __restrict__ bbase,
                        int* __restrict__ gcur, int nb, int total) {
    __shared__ int s[512];
    int tid = threadIdx.x;
    int v = (tid < nb) ? bcnt[tid] : 0;
    s[tid] = v;
    __syncthreads();
    for (int o = 1; o < 512; o <<= 1) {
        int t = (tid >= o) ? s[tid - o] : 0;
        __syncthreads();
        s[tid] += t;
        __syncthreads();
    }
    if (tid < nb) { int ex = s[tid] - v; bbase[tid] = ex; gcur[tid] = ex; }
    if (tid == 0) bbase[nb] = total;
}

// ---- partition packed records (local_key<<17 | other) into bucket regions ----
__global__ void k_part(const int* __restrict__ key, const int* __restrict__ oth,
                       int* __restrict__ gcur, unsigned int* __restrict__ rec,
                       int nb, int ne) {
    __shared__ int cnt[NBU];
    __shared__ int gbase[NBU];
    int tid = threadIdx.x;
    for (int b = tid; b < nb; b += 256) cnt[b] = 0;
    __syncthreads();
    int base = blockIdx.x * CHUNK;
    int myk[16]; int myb[16]; unsigned int myr[16];
#pragma unroll
    for (int k = 0; k < 16; k++) {
        int j = base + tid + k * 256;
        myb[k] = -1;
        if (j < ne) {
            int d = key[j];
            int b = d >> 8;
            myb[k] = b;
            myr[k] = ((unsigned int)(d & 255) << 17) | (unsigned int)oth[j];
            myk[k] = atomicAdd(&cnt[b], 1);
        }
    }
    __syncthreads();
    for (int b = tid; b < nb; b += 256) {
        int c = cnt[b];
        if (c) gbase[b] = atomicAdd(&gcur[b], c);
    }
    __syncthreads();
#pragma unroll
    for (int k = 0; k < 16; k++) {
        if (myb[k] >= 0) rec[gbase[myb[k]] + myk[k]] = myr[k];
    }
}

// ---- per-bucket local fill: exclusive ownership, LDS counters/scan ----
__global__ void k_local(const unsigned int* __restrict__ rec, const int* __restrict__ bbase,
                        int* __restrict__ rp, int* __restrict__ col, int n_nodes) {
    __shared__ int cnt[256];
    __shared__ int off[256];
    int tid = threadIdx.x;
    int b = blockIdx.x;
    int beg = bbase[b], end = bbase[b + 1];
    cnt[tid] = 0;
    __syncthreads();
    for (int j = beg + tid; j < end; j += 256)
        atomicAdd(&cnt[rec[j] >> 17], 1);
    __syncthreads();
    int v = cnt[tid];
    off[tid] = v;
    __syncthreads();
    for (int o = 1; o < 256; o <<= 1) {
        int t = (tid >= o) ? off[tid - o] : 0;
        __syncthreads();
        off[tid] += t;
        __syncthreads();
    }
    int ex = off[tid] - v;
    int node = b * 256 + tid;
    if (node <= n_nodes) rp[node] = beg + ex;
    cnt[tid] = ex;
    __syncthreads();
    for (int j = beg + tid; j < end; j += 256) {
        unsigned int r = rec[j];
        int ln = r >> 17;
        int p = atomicAdd(&cnt[ln], 1);
        col[beg + p] = (int)(r & 0x1FFFF);
    }
}

// ---- pull aggregation, bf16 gather + f32 self, fused finalize (+optional bf16 shadow) ----
// out = mean(bf16 feat[neighbors]) + self*sw ; out may alias self (per-thread RAW only)
__global__ void k_agg_bf(const unsigned short* __restrict__ feat, const float* self,
                         const float* __restrict__ sw, const int* __restrict__ rp,
                         const int* __restrict__ cols, float* out,
                         unsigned short* out_bf, int n_dst) {
    int gtid = blockIdx.x * blockDim.x + threadIdx.x;
    int w = gtid >> 6;
    int lane = threadIdx.x & 63;
    if (w >= n_dst) return;
    int beg = rp[w], end = rp[w + 1];
    float a0 = 0.f, a1 = 0.f, a2 = 0.f, a3 = 0.f;
    int j = beg;
    for (; j + 4 <= end; j += 4) {          // 4 independent 128B gathers in flight
        int c0 = cols[j], c1 = cols[j + 1], c2 = cols[j + 2], c3 = cols[j + 3];
        a0 += bf2f(feat[c0 * D + lane]);
        a1 += bf2f(feat[c1 * D + lane]);
        a2 += bf2f(feat[c2 * D + lane]);
        a3 += bf2f(feat[c3 * D + lane]);
    }
    for (; j < end; ++j) a0 += bf2f(feat[cols[j] * D + lane]);
    float acc = (a0 + a1) + (a2 + a3);
    int dgr = end - beg;
    float inv = (dgr > 0) ? (1.0f / (float)dgr) : 0.0f;
    float r = acc * inv + self[w * D + lane] * sw[w];
    out[w * D + lane] = r;
    if (out_bf) out_bf[w * D + lane] = f2bf(r);
}

extern "C" void kernel_launch(void* const* d_in, const int* in_sizes, int n_in,
                              void* d_out, int out_size, void* d_ws, size_t ws_size,
                              hipStream_t stream) {
    const float* user_emb = (const float*)d_in[0];
    const float* item_emb = (const float*)d_in[1];
    const float* u_sw     = (const float*)d_in[2];
    const float* i_sw     = (const float*)d_in[3];
    const int*   esrc     = (const int*)d_in[4];   // user endpoint
    const int*   edst     = (const int*)d_in[5];   // item endpoint

    float* out_u = (float*)d_out;          // NU*64 f32
    float* out_i = out_u + NU * D;         // NI*64 f32

    // ---- workspace layout (~35.8 MB, with aliasing) ----
    int* bcnt    = (int*)d_ws;                            // NB_TOT
    int* bbase_i = bcnt + NB_TOT;                         // NBI+1
    int* bbase_u = bbase_i + NBI + 1;                     // NBU+1
    int* gcur_i  = bbase_u + NBU + 1;                     // NBI
    int* gcur_u  = gcur_i + NBI;                          // NBU
    int* rp_i    = gcur_u + NBU;                          // NI+1
    int* rp_u    = rp_i + NI + 1;                         // NU+1
    int* col_i   = rp_u + NU + 1;                         // NE
    int* col_u   = col_i + NE;                            // NE
    unsigned int* rec_i = (unsigned int*)(col_u + NE);    // NE   (dead after build)
    unsigned int* rec_u = rec_i + NE;                     // NE   (dead after build)
    unsigned short* i1_bf = (unsigned short*)rec_i;       // NI*64 us, ALIASES rec (6.4MB<=8MB)
    unsigned short* u_bf  = (unsigned short*)(rec_u + NE);// NU*64 us (u0 shadow)
    unsigned short* u1_bf = u_bf;                         // ALIASES u_bf (u0 dead after R1-item)
    unsigned short* i_bf  = u_bf + (size_t)NU * D;        // NI*64 us (i0 shadow)

    hipMemsetAsync(bcnt, 0, NB_TOT * sizeof(int), stream);

    const int B = 256;

    // ---- CSR build, bucketed ----
    k_bhist<<<512, B, 0, stream>>>(esrc, edst, bcnt, NE);
    k_bscan<<<1, 512, 0, stream>>>(bcnt, bbase_i, gcur_i, NBI, NE);
    k_bscan<<<1, 512, 0, stream>>>(bcnt + NBI, bbase_u, gcur_u, NBU, NE);
    int pgrid = (NE + CHUNK - 1) / CHUNK;
    k_part<<<pgrid, B, 0, stream>>>(edst, esrc, gcur_i, rec_i, NBI, NE);
    k_part<<<pgrid, B, 0, stream>>>(esrc, edst, gcur_u, rec_u, NBU, NE);
    k_local<<<NBI, B, 0, stream>>>(rec_i, bbase_i, rp_i, col_i, NI);
    k_local<<<NBU, B, 0, stream>>>(rec_u, bbase_u, rp_u, col_u, NU);

    // ---- bf16 shadows of the input tables ----
    k_tobf16<<<(NU * D / 4 + B - 1) / B, B, 0, stream>>>(user_emb, u_bf, NU * D / 4);
    k_tobf16<<<(NI * D / 4 + B - 1) / B, B, 0, stream>>>(item_emb, i_bf, NI * D / 4);

    int gi = (NI + 3) / 4;
    int gu = (NU + 3) / 4;

    // ---- round 1 ----
    // i1 = mean(u0_bf) + i0*i_sw -> out_i (f32) + i1_bf (rec region is dead now)
    k_agg_bf<<<gi, B, 0, stream>>>(u_bf, item_emb, i_sw, rp_i, col_i, out_i, i1_bf, NI);
    // u1 = mean(i0_bf) + u0*u_sw -> out_u (f32) + u1_bf (aliases u_bf; u0_bf dead)
    k_agg_bf<<<gu, B, 0, stream>>>(i_bf, user_emb, u_sw, rp_u, col_u, out_u, u1_bf, NU);

    // ---- round 2 (in-place finalize; self reads precede writes per-thread) ----
    // i2 = mean(u1_bf) + i1*i_sw -> out_i
    k_agg_bf<<<gi, B, 0, stream>>>(u1_bf, out_i, i_sw, rp_i, col_i, out_i, nullptr, NI);
    // u2 = mean(i1_bf) + u1*u_sw -> out_u
    k_agg_bf<<<gu, B, 0, stream>>>(i1_bf, out_u, u_sw, rp_u, col_u, out_u, nullptr, NU);
}

// Round 5
// 361.677 us; speedup vs baseline: 1.0242x; 1.0242x over previous
//
#include <hip/hip_runtime.h>

#define NU 100000
#define NI 50000
#define NE 1000000
#define D  64
#define NBI 196            // item buckets, 256 items each
#define NBU 391            // user buckets, 256 users each
#define NB_TOT (NBI + NBU)
#define CHUNK 4096         // edges per k_part block (16 per thread)

__device__ __forceinline__ unsigned short f2bf(float f) {
    unsigned int u = __float_as_uint(f);
    u += 0x7FFFu + ((u >> 16) & 1u);   // round-to-nearest-even
    return (unsigned short)(u >> 16);
}
__device__ __forceinline__ float bf2f(unsigned short h) {
    return __uint_as_float(((unsigned int)h) << 16);
}

// ---- f32 table -> bf16 shadow table (vectorized 4-wide) ----
__global__ void k_tobf16(const float* __restrict__ in, unsigned short* __restrict__ out, int n4) {
    int i = blockIdx.x * blockDim.x + threadIdx.x;
    if (i < n4) {
        float4 f = ((const float4*)in)[i];
        ushort4 h;
        h.x = f2bf(f.x); h.y = f2bf(f.y); h.z = f2bf(f.z); h.w = f2bf(f.w);
        ((ushort4*)out)[i] = h;
    }
}

// ---- bucket histograms for both partitions in one pass ----
__global__ void k_bhist(const int* __restrict__ esrc, const int* __restrict__ edst,
                        int* __restrict__ bcnt, int ne) {
    __shared__ int h[NB_TOT];
    for (int b = threadIdx.x; b < NB_TOT; b += blockDim.x) h[b] = 0;
    __syncthreads();
    int stride = gridDim.x * blockDim.x;
    for (int e = blockIdx.x * blockDim.x + threadIdx.x; e < ne; e += stride) {
        atomicAdd(&h[edst[e] >> 8], 1);
        atomicAdd(&h[NBI + (esrc[e] >> 8)], 1);
    }
    __syncthreads();
    for (int b = threadIdx.x; b < NB_TOT; b += blockDim.x) {
        int v = h[b];
        if (v) atomicAdd(&bcnt[b], v);
    }
}

// ---- tiny exclusive scan of bucket counts -> bucket bases + partition cursors ----
__global__ void k_bscan(const int* __restrict__ bcnt, int* __restrict__ bbase,
                        int* __restrict__ gcur, int nb, int total) {
    __shared__ int s[512];
    int tid = threadIdx.x;
    int v = (tid < nb) ? bcnt[tid] : 0;
    s[tid] = v;
    __syncthreads();
    for (int o = 1; o < 512; o <<= 1) {
        int t = (tid >= o) ? s[tid - o] : 0;
        __syncthreads();
        s[tid] += t;
        __syncthreads();
    }
    if (tid < nb) { int ex = s[tid] - v; bbase[tid] = ex; gcur[tid] = ex; }
    if (tid == 0) bbase[nb] = total;
}

// ---- partition packed records (local_key<<17 | other) into bucket regions ----
__global__ void k_part(const int* __restrict__ key, const int* __restrict__ oth,
                       int* __restrict__ gcur, unsigned int* __restrict__ rec,
                       int nb, int ne) {
    __shared__ int cnt[NBU];
    __shared__ int gbase[NBU];
    int tid = threadIdx.x;
    for (int b = tid; b < nb; b += 256) cnt[b] = 0;
    __syncthreads();
    int base = blockIdx.x * CHUNK;
    int myk[16]; int myb[16]; unsigned int myr[16];
#pragma unroll
    for (int k = 0; k < 16; k++) {
        int j = base + tid + k * 256;
        myb[k] = -1;
        if (j < ne) {
            int d = key[j];
            int b = d >> 8;
            myb[k] = b;
            myr[k] = ((unsigned int)(d & 255) << 17) | (unsigned int)oth[j];
            myk[k] = atomicAdd(&cnt[b], 1);
        }
    }
    __syncthreads();
    for (int b = tid; b < nb; b += 256) {
        int c = cnt[b];
        if (c) gbase[b] = atomicAdd(&gcur[b], c);
    }
    __syncthreads();
#pragma unroll
    for (int k = 0; k < 16; k++) {
        if (myb[k] >= 0) rec[gbase[myb[k]] + myk[k]] = myr[k];
    }
}

// ---- per-bucket local fill: exclusive ownership, LDS counters/scan ----
__global__ void k_local(const unsigned int* __restrict__ rec, const int* __restrict__ bbase,
                        int* __restrict__ rp, int* __restrict__ col, int n_nodes) {
    __shared__ int cnt[256];
    __shared__ int off[256];
    int tid = threadIdx.x;
    int b = blockIdx.x;
    int beg = bbase[b], end = bbase[b + 1];
    cnt[tid] = 0;
    __syncthreads();
    for (int j = beg + tid; j < end; j += 256)
        atomicAdd(&cnt[rec[j] >> 17], 1);
    __syncthreads();
    int v = cnt[tid];
    off[tid] = v;
    __syncthreads();
    for (int o = 1; o < 256; o <<= 1) {
        int t = (tid >= o) ? off[tid - o] : 0;
        __syncthreads();
        off[tid] += t;
        __syncthreads();
    }
    int ex = off[tid] - v;
    int node = b * 256 + tid;
    if (node <= n_nodes) rp[node] = beg + ex;
    cnt[tid] = ex;
    __syncthreads();
    for (int j = beg + tid; j < end; j += 256) {
        unsigned int r = rec[j];
        int ln = r >> 17;
        int p = atomicAdd(&cnt[ln], 1);
        col[beg + p] = (int)(r & 0x1FFFF);
    }
}

// ---- pull aggregation v2: 4 edges per gather instruction, 8 edges in flight ----
// lane = (sub = lane>>4 in [0,4), li = lane&15); each lane gathers ushort4 (4 bf16 dims)
// of edge j0+sub (and j0+4+sub). Cross-sub reduce via shfl_xor; lanes 0-15 finalize.
// out = mean(bf16 feat[nbrs]) + self*sw ; out may alias self (per-thread RAW only)
__global__ void k_agg_bf(const unsigned short* __restrict__ feat, const float* self,
                         const float* __restrict__ sw, const int* __restrict__ rp,
                         const int* __restrict__ cols, float* out,
                         unsigned short* out_bf, int n_dst) {
    int gtid = blockIdx.x * blockDim.x + threadIdx.x;
    int w = gtid >> 6;
    int lane = threadIdx.x & 63;
    if (w >= n_dst) return;
    int sub = lane >> 4;
    int li  = lane & 15;
    int beg = rp[w], end = rp[w + 1];

    float4 a0 = make_float4(0.f, 0.f, 0.f, 0.f);
    float4 a1 = make_float4(0.f, 0.f, 0.f, 0.f);

    for (int j0 = beg; j0 < end; j0 += 8) {
        int e0 = j0 + sub;
        int e1 = e0 + 4;
        bool v0 = e0 < end;
        bool v1 = e1 < end;
        int c0 = 0, c1 = 0;
        if (v0) c0 = cols[e0];
        if (v1) c1 = cols[e1];
        ushort4 h0, h1;
        if (v0) h0 = *(const ushort4*)(feat + (size_t)c0 * D + li * 4);
        if (v1) h1 = *(const ushort4*)(feat + (size_t)c1 * D + li * 4);
        if (v0) {
            a0.x += bf2f(h0.x); a0.y += bf2f(h0.y);
            a0.z += bf2f(h0.z); a0.w += bf2f(h0.w);
        }
        if (v1) {
            a1.x += bf2f(h1.x); a1.y += bf2f(h1.y);
            a1.z += bf2f(h1.z); a1.w += bf2f(h1.w);
        }
    }
    a0.x += a1.x; a0.y += a1.y; a0.z += a1.z; a0.w += a1.w;
    // reduce across the 4 sub-groups (lanes differing in bits 4 and 5)
    a0.x += __shfl_xor(a0.x, 16); a0.y += __shfl_xor(a0.y, 16);
    a0.z += __shfl_xor(a0.z, 16); a0.w += __shfl_xor(a0.w, 16);
    a0.x += __shfl_xor(a0.x, 32); a0.y += __shfl_xor(a0.y, 32);
    a0.z += __shfl_xor(a0.z, 32); a0.w += __shfl_xor(a0.w, 32);

    if (sub == 0) {
        int dgr = end - beg;
        float inv = (dgr > 0) ? (1.0f / (float)dgr) : 0.0f;
        float swv = sw[w];
        float4 s = *(const float4*)(self + (size_t)w * D + li * 4);
        float4 r;
        r.x = a0.x * inv + s.x * swv;
        r.y = a0.y * inv + s.y * swv;
        r.z = a0.z * inv + s.z * swv;
        r.w = a0.w * inv + s.w * swv;
        *(float4*)(out + (size_t)w * D + li * 4) = r;
        if (out_bf) {
            ushort4 hb;
            hb.x = f2bf(r.x); hb.y = f2bf(r.y); hb.z = f2bf(r.z); hb.w = f2bf(r.w);
            *(ushort4*)(out_bf + (size_t)w * D + li * 4) = hb;
        }
    }
}

extern "C" void kernel_launch(void* const* d_in, const int* in_sizes, int n_in,
                              void* d_out, int out_size, void* d_ws, size_t ws_size,
                              hipStream_t stream) {
    const float* user_emb = (const float*)d_in[0];
    const float* item_emb = (const float*)d_in[1];
    const float* u_sw     = (const float*)d_in[2];
    const float* i_sw     = (const float*)d_in[3];
    const int*   esrc     = (const int*)d_in[4];   // user endpoint
    const int*   edst     = (const int*)d_in[5];   // item endpoint

    float* out_u = (float*)d_out;          // NU*64 f32
    float* out_i = out_u + NU * D;         // NI*64 f32

    // ---- workspace layout (~35.8 MB, with aliasing) ----
    int* bcnt    = (int*)d_ws;                            // NB_TOT
    int* bbase_i = bcnt + NB_TOT;                         // NBI+1
    int* bbase_u = bbase_i + NBI + 1;                     // NBU+1
    int* gcur_i  = bbase_u + NBU + 1;                     // NBI
    int* gcur_u  = gcur_i + NBI;                          // NBU
    int* rp_i    = gcur_u + NBU;                          // NI+1
    int* rp_u    = rp_i + NI + 1;                         // NU+1
    int* col_i   = rp_u + NU + 1;                         // NE
    int* col_u   = col_i + NE;                            // NE
    uintptr_t pa = ((uintptr_t)(col_u + NE) + 15) & ~(uintptr_t)15;  // 16B align
    unsigned int* rec_i = (unsigned int*)pa;              // NE   (dead after build)
    unsigned int* rec_u = rec_i + NE;                     // NE   (dead after build)
    unsigned short* i1_bf = (unsigned short*)rec_i;       // NI*64 us, ALIASES rec (6.4MB<=8MB)
    unsigned short* u_bf  = (unsigned short*)(rec_u + NE);// NU*64 us (u0 shadow), 16B-aligned
    unsigned short* u1_bf = u_bf;                         // ALIASES u_bf (u0 dead after R1-item)
    unsigned short* i_bf  = u_bf + (size_t)NU * D;        // NI*64 us (i0 shadow)

    hipMemsetAsync(bcnt, 0, NB_TOT * sizeof(int), stream);

    const int B = 256;

    // ---- CSR build, bucketed ----
    k_bhist<<<512, B, 0, stream>>>(esrc, edst, bcnt, NE);
    k_bscan<<<1, 512, 0, stream>>>(bcnt, bbase_i, gcur_i, NBI, NE);
    k_bscan<<<1, 512, 0, stream>>>(bcnt + NBI, bbase_u, gcur_u, NBU, NE);
    int pgrid = (NE + CHUNK - 1) / CHUNK;
    k_part<<<pgrid, B, 0, stream>>>(edst, esrc, gcur_i, rec_i, NBI, NE);
    k_part<<<pgrid, B, 0, stream>>>(esrc, edst, gcur_u, rec_u, NBU, NE);
    k_local<<<NBI, B, 0, stream>>>(rec_i, bbase_i, rp_i, col_i, NI);
    k_local<<<NBU, B, 0, stream>>>(rec_u, bbase_u, rp_u, col_u, NU);

    // ---- bf16 shadows of the input tables ----
    k_tobf16<<<(NU * D / 4 + B - 1) / B, B, 0, stream>>>(user_emb, u_bf, NU * D / 4);
    k_tobf16<<<(NI * D / 4 + B - 1) / B, B, 0, stream>>>(item_emb, i_bf, NI * D / 4);

    int gi = (NI + 3) / 4;
    int gu = (NU + 3) / 4;

    // ---- round 1 ----
    // i1 = mean(u0_bf) + i0*i_sw -> out_i (f32) + i1_bf (rec region dead now)
    k_agg_bf<<<gi, B, 0, stream>>>(u_bf, item_emb, i_sw, rp_i, col_i, out_i, i1_bf, NI);
    // u1 = mean(i0_bf) + u0*u_sw -> out_u (f32) + u1_bf (aliases u_bf; u0_bf dead)
    k_agg_bf<<<gu, B, 0, stream>>>(i_bf, user_emb, u_sw, rp_u, col_u, out_u, u1_bf, NU);

    // ---- round 2 (in-place finalize; self reads precede writes per-thread) ----
    // i2 = mean(u1_bf) + i1*i_sw -> out_i
    k_agg_bf<<<gi, B, 0, stream>>>(u1_bf, out_i, i_sw, rp_i, col_i, out_i, nullptr, NI);
    // u2 = mean(i1_bf) + u1*u_sw -> out_u
    k_agg_bf<<<gu, B, 0, stream>>>(i1_bf, out_u, u_sw, rp_u, col_u, out_u, nullptr, NU);
}